// Round 4
// baseline (2588.634 us; speedup 1.0000x reference)
//
#include <hip/hip_runtime.h>
#include <math.h>

#define NCLS 40
#define BSZ 32          // dst nodes per bucket
#define BCAP 768        // slots per bucket (avg fill 512, P(overflow) ~ 1e-27)

using f16x8 = __attribute__((ext_vector_type(8))) _Float16;
using f16x2 = __attribute__((ext_vector_type(2))) _Float16;
using f32x4 = __attribute__((ext_vector_type(4))) float;

// ---------------- bucketed edge build (no exact CSR) ----------------
__global__ void init_cur(int* __restrict__ bcur, int nbk) {
  int i = blockIdx.x * 256 + threadIdx.x;
  if (i < nbk) bcur[i] = i * BCAP;
}

// Append edges to dst-bucket regions. Atomic-cursor appends cluster writes to
// a cache line in TIME (consecutive slots claimed ~simultaneously), and the
// (bucket&7)==XCD partition gives each line one L2 owner -> lines merge and
// write back once (fixes the 8x partial-line write amplification of CSR fill).
__global__ __launch_bounds__(256) void append_part(const int* __restrict__ ei,
    const float* __restrict__ ew, int* __restrict__ bcur,
    int2* __restrict__ bedge, int e) {
  int part = blockIdx.x & 7;
  int grp = blockIdx.x >> 3;
  int ngrp = gridDim.x >> 3;
  for (int i = grp * 256 + threadIdx.x; i < e; i += ngrp * 256) {
    int d = ei[e + i];                 // dst row of edge_index
    int b = d >> 5;
    if ((b & 7) == part) {
      int s = ei[i];
      float w = ew[i];
      int slot = atomicAdd(&bcur[b], 1);
      if (slot < b * BCAP + BCAP)      // overflow guard (never in practice)
        bedge[slot] = make_int2(s | ((d & 31) << 20), __float_as_int(w));
    }
  }
}

// ---------------- weight transpose + fp16 convert ----------------
__global__ void convert_wt(const float* __restrict__ W, _Float16* __restrict__ Wt) {
  // block c: Wt[c][k] = fp16(W[k][c]); coalesced writes, column reads L2-hit
  int c = blockIdx.x;
  int k = threadIdx.x;
  Wt[c * 128 + k] = (_Float16)W[k * 128 + c];
}

// ------- MFMA GEMM: Y[n,128](f16) = A[n,128] @ W  (Wt = W^T, f16) -------
// A32: read fp32 A directly (fuses the x->fp16 convert pass into layer 1).
template<bool A32>
__global__ __launch_bounds__(256) void gemm_f16(const void* __restrict__ Av,
    const _Float16* __restrict__ Wt, _Float16* __restrict__ Y, int n) {
  __shared__ _Float16 Ys[64][136];   // bounce for coalesced stores
  int t = threadIdx.x;
  int wv = t >> 6, l = t & 63;
  int r0 = blockIdx.x * 64 + wv * 16;
  int arow = r0 + (l & 15);
  int kq = (l >> 4) * 8;
  bool rowok = arow < n;
  f32x4 acc[8] = {};
  for (int kc = 0; kc < 128; kc += 32) {
    f16x8 a = {};
    if (rowok) {
      if constexpr (A32) {
        const float* xp = (const float*)Av + (size_t)arow * 128 + kc + kq;
        float4 u0 = *(const float4*)xp;
        float4 u1 = *(const float4*)(xp + 4);
        a[0] = (_Float16)u0.x; a[1] = (_Float16)u0.y;
        a[2] = (_Float16)u0.z; a[3] = (_Float16)u0.w;
        a[4] = (_Float16)u1.x; a[5] = (_Float16)u1.y;
        a[6] = (_Float16)u1.z; a[7] = (_Float16)u1.w;
      } else {
        a = *(const f16x8*)((const _Float16*)Av + (size_t)arow * 128 + kc + kq);
      }
    }
    #pragma unroll
    for (int j = 0; j < 8; j++) {
      f16x8 b = *(const f16x8*)(Wt + (size_t)(j * 16 + (l & 15)) * 128 + kc + kq);
      acc[j] = __builtin_amdgcn_mfma_f32_16x16x32_f16(a, b, acc[j], 0, 0, 0);
    }
  }
  #pragma unroll
  for (int j = 0; j < 8; j++)
    #pragma unroll
    for (int i = 0; i < 4; i++)
      Ys[wv * 16 + (l >> 4) * 4 + i][j * 16 + (l & 15)] = (_Float16)acc[j][i];
  __syncthreads();
  int r = t >> 2;
  int c0 = (t & 3) * 32;
  int grow = blockIdx.x * 64 + r;
  if (grow < n) {
    #pragma unroll
    for (int i = 0; i < 4; i++) {
      f16x8 v = *(const f16x8*)&Ys[r][c0 + i * 8];
      *(f16x8*)(Y + (size_t)grow * 128 + c0 + i * 8) = v;
    }
  }
}

// -- bucketed SpMM + self + bias + ReLU: H = relu(Y + A Y + b) --
// One block per 32-node bucket; fp32 LDS accumulators; split-channel lanes
// (ch l and l+64) keep ds_add_f32 bank-conflict-free (bank = l%32, 2-way).
__global__ __launch_bounds__(256) void spmm_bucket(const _Float16* __restrict__ Y,
    const int* __restrict__ bcur, const int2* __restrict__ bedge,
    const float* __restrict__ bias, _Float16* __restrict__ H, int n) {
  __shared__ float acc[BSZ][128];    // 16 KB
  int t = threadIdx.x;
  int b = blockIdx.x;
  {
    f32x4 z = {0.f, 0.f, 0.f, 0.f};
    float* af = &acc[0][0];
    #pragma unroll
    for (int i = 0; i < 4; i++) *(f32x4*)(af + (i * 256 + t) * 4) = z;
  }
  __syncthreads();
  int wv = t >> 6, l = t & 63;
  int e = b * BCAP + wv;
  int e1 = min(bcur[b], b * BCAP + BCAP);
  for (; e + 12 < e1; e += 16) {     // 4 edges/wave in flight
    int2 p0 = bedge[e], p1 = bedge[e + 4], p2 = bedge[e + 8], p3 = bedge[e + 12];
    const _Float16* y0 = Y + (size_t)(p0.x & 0xFFFFF) * 128;
    const _Float16* y1 = Y + (size_t)(p1.x & 0xFFFFF) * 128;
    const _Float16* y2 = Y + (size_t)(p2.x & 0xFFFFF) * 128;
    const _Float16* y3 = Y + (size_t)(p3.x & 0xFFFFF) * 128;
    float a0x = (float)y0[l], a0y = (float)y0[l + 64];
    float a1x = (float)y1[l], a1y = (float)y1[l + 64];
    float a2x = (float)y2[l], a2y = (float)y2[l + 64];
    float a3x = (float)y3[l], a3y = (float)y3[l + 64];
    int d0 = (unsigned)p0.x >> 20, d1 = (unsigned)p1.x >> 20;
    int d2 = (unsigned)p2.x >> 20, d3 = (unsigned)p3.x >> 20;
    float w0 = __int_as_float(p0.y), w1 = __int_as_float(p1.y);
    float w2 = __int_as_float(p2.y), w3 = __int_as_float(p3.y);
    atomicAdd(&acc[d0][l], w0 * a0x); atomicAdd(&acc[d0][l + 64], w0 * a0y);
    atomicAdd(&acc[d1][l], w1 * a1x); atomicAdd(&acc[d1][l + 64], w1 * a1y);
    atomicAdd(&acc[d2][l], w2 * a2x); atomicAdd(&acc[d2][l + 64], w2 * a2y);
    atomicAdd(&acc[d3][l], w3 * a3x); atomicAdd(&acc[d3][l + 64], w3 * a3y);
  }
  for (; e < e1; e += 4) {
    int2 p = bedge[e];
    const _Float16* yr = Y + (size_t)(p.x & 0xFFFFF) * 128;
    int dl = (unsigned)p.x >> 20;
    float w = __int_as_float(p.y);
    atomicAdd(&acc[dl][l], w * (float)yr[l]);
    atomicAdd(&acc[dl][l + 64], w * (float)yr[l + 64]);
  }
  __syncthreads();
  int dl = t >> 3, c0 = (t & 7) * 16;
  int node = b * BSZ + dl;
  if (node < n) {
    const _Float16* yr = Y + (size_t)node * 128 + c0;
    f16x8 v0 = *(const f16x8*)yr;
    f16x8 v1 = *(const f16x8*)(yr + 8);
    f16x8 o0, o1;
    #pragma unroll
    for (int q = 0; q < 8; q++) {
      float z0 = (float)v0[q] + acc[dl][c0 + q] + bias[c0 + q];
      float z1 = (float)v1[q] + acc[dl][c0 + 8 + q] + bias[c0 + 8 + q];
      o0[q] = (_Float16)fmaxf(z0, 0.f);
      o1[q] = (_Float16)fmaxf(z1, 0.f);
    }
    _Float16* hr = H + (size_t)node * 128 + c0;
    *(f16x8*)hr = o0;
    *(f16x8*)(hr + 8) = o1;
  }
}

// -------- FC over concat(h1,h2)(f16) + log_softmax (fp32 compute) --------
__global__ __launch_bounds__(256) void fc_lsm(const _Float16* __restrict__ H1,
    const _Float16* __restrict__ H2, const float* __restrict__ Wfc,
    const float* __restrict__ bfc, float* __restrict__ out, int n) {
  __shared__ float Wl[256 * NCLS];        // 40 KB, [k][c] layout
  __shared__ float Hs[64][132];           // 33 KB, transposed chunk Hs[k][r]
  int t = threadIdx.x;
  for (int i = t; i < 256 * NCLS; i += 256) Wl[i] = Wfc[i];
  int tx = t & 7, ty = t >> 3;            // tx: 5-col group (8x5=40), ty: 4-row group
  int row0 = blockIdx.x * 128;
  float acc[4][5] = {};
  for (int kc = 0; kc < 256; kc += 64) {
    { // stage 128 rows x 64 k of concat(H1,H2), transposed, f16 -> f32
      int r = t & 127;
      int half = t >> 7;
      int row = row0 + r;
      const _Float16* src = (kc < 128)
          ? (H1 + (size_t)row * 128 + kc + half * 32)
          : (H2 + (size_t)row * 128 + (kc - 128) + half * 32);
      if (row < n) {
        #pragma unroll
        for (int i = 0; i < 4; i++) {
          f16x8 v = ((const f16x8*)src)[i];
          #pragma unroll
          for (int q = 0; q < 8; q++) Hs[half * 32 + i * 8 + q][r] = (float)v[q];
        }
      } else {
        #pragma unroll
        for (int k = 0; k < 32; k++) Hs[half * 32 + k][r] = 0.f;
      }
    }
    __syncthreads();
    #pragma unroll 4
    for (int k = 0; k < 64; k++) {
      float4 a = *(const float4*)&Hs[k][ty * 4];
      const float* wrow = &Wl[(kc + k) * NCLS + tx * 5];
      float b_[5];
      #pragma unroll
      for (int j = 0; j < 5; j++) b_[j] = wrow[j];
      #pragma unroll
      for (int j = 0; j < 5; j++) {
        acc[0][j] = fmaf(a.x, b_[j], acc[0][j]);
        acc[1][j] = fmaf(a.y, b_[j], acc[1][j]);
        acc[2][j] = fmaf(a.z, b_[j], acc[2][j]);
        acc[3][j] = fmaf(a.w, b_[j], acc[3][j]);
      }
    }
    __syncthreads();
  }
  int c0 = tx * 5;
  float bv[5];
  #pragma unroll
  for (int j = 0; j < 5; j++) bv[j] = bfc[c0 + j];
  #pragma unroll
  for (int i = 0; i < 4; i++) {
    float lg[5];
    #pragma unroll
    for (int j = 0; j < 5; j++) lg[j] = acc[i][j] + bv[j];
    float m = lg[0];
    #pragma unroll
    for (int j = 1; j < 5; j++) m = fmaxf(m, lg[j]);
    m = fmaxf(m, __shfl_xor(m, 1));
    m = fmaxf(m, __shfl_xor(m, 2));
    m = fmaxf(m, __shfl_xor(m, 4));       // 8 lanes (same ty) own one row's 40 cols
    float ssum = 0.f;
    #pragma unroll
    for (int j = 0; j < 5; j++) ssum += __expf(lg[j] - m);
    ssum += __shfl_xor(ssum, 1);
    ssum += __shfl_xor(ssum, 2);
    ssum += __shfl_xor(ssum, 4);
    float lse = m + __logf(ssum);
    int row = row0 + ty * 4 + i;
    if (row < n) {
      #pragma unroll
      for (int j = 0; j < 5; j++) out[(size_t)row * NCLS + c0 + j] = lg[j] - lse;
    }
  }
}

extern "C" void kernel_launch(void* const* d_in, const int* in_sizes, int n_in,
                              void* d_out, int out_size, void* d_ws, size_t ws_size,
                              hipStream_t stream) {
  const float* x   = (const float*)d_in[0];
  const int*   ei  = (const int*)d_in[1];
  const float* ew  = (const float*)d_in[2];
  const float* W1  = (const float*)d_in[3];
  const float* b1  = (const float*)d_in[4];
  const float* W2  = (const float*)d_in[5];
  const float* b2  = (const float*)d_in[6];
  const float* Wfc = (const float*)d_in[7];
  const float* bfc = (const float*)d_in[8];
  float* out = (float*)d_out;
  int n = in_sizes[0] / 128;     // 100000
  int e = in_sizes[2];           // 1600000
  int nbk = (n + BSZ - 1) / BSZ; // 3125 buckets

  // workspace partition (~96 MB)
  char* ws = (char*)d_ws;
  size_t off = 0;
  auto alloc = [&](size_t bytes) -> void* {
    void* p = ws + off; off += (bytes + 255) & ~(size_t)255; return p;
  };
  int*      bcur = (int*)alloc((size_t)nbk * 4);
  int2*     bedge = (int2*)alloc((size_t)nbk * BCAP * 8);
  _Float16* w1t  = (_Float16*)alloc(128 * 128 * 2);
  _Float16* w2t  = (_Float16*)alloc(128 * 128 * 2);
  _Float16* y    = (_Float16*)alloc((size_t)n * 128 * 2);
  _Float16* h1   = (_Float16*)alloc((size_t)n * 128 * 2);
  _Float16* h2   = (_Float16*)alloc((size_t)n * 128 * 2);

  // bucketed edge build
  init_cur<<<(nbk + 255) / 256, 256, 0, stream>>>(bcur, nbk);
  append_part<<<8 * 104, 256, 0, stream>>>(ei, ew, bcur, bedge, e);

  // weight converts
  convert_wt<<<128, 128, 0, stream>>>(W1, w1t);
  convert_wt<<<128, 128, 0, stream>>>(W2, w2t);

  int gb = (n + 63) / 64;
  // layer 1: y = x@W1 ; h1 = relu(y + A y + b1)   (x fp32 read fused)
  gemm_f16<true><<<gb, 256, 0, stream>>>((const void*)x, w1t, y, n);
  spmm_bucket<<<nbk, 256, 0, stream>>>(y, bcur, bedge, b1, h1, n);
  // layer 2: y = h1@W2 ; h2 = relu(y + A y + b2)
  gemm_f16<false><<<gb, 256, 0, stream>>>((const void*)h1, w2t, y, n);
  spmm_bucket<<<nbk, 256, 0, stream>>>(y, bcur, bedge, b2, h2, n);
  // FC + log_softmax
  fc_lsm<<<(n + 127) / 128, 256, 0, stream>>>(h1, h2, Wfc, bfc, out, n);
}

// Round 5
// 567.292 us; speedup vs baseline: 4.5631x; 4.5631x over previous
//
#include <hip/hip_runtime.h>
#include <math.h>

#define NCLS 40
#define BSZ 32          // dst nodes per bucket
#define BCAP 768        // slots per bucket (avg fill 512, P(overflow) ~ 1e-27)

using f16x8 = __attribute__((ext_vector_type(8))) _Float16;
using f16x2 = __attribute__((ext_vector_type(2))) _Float16;
using f32x4 = __attribute__((ext_vector_type(4))) float;

// ---------------- bucketed edge build ----------------
__global__ void init_cur(int* __restrict__ bcur, int nbk) {
  int i = blockIdx.x * 256 + threadIdx.x;
  if (i < nbk) bcur[i] = i * BCAP;
}

// Append edges into dst-bucket regions (bucket = dst>>5). Atomic-cursor appends
// cluster a line's 8 records in TIME; (bucket&7)==XCD partition gives each line
// one L2 owner. Replaces count_deg + exact-CSR scatter fill.
__global__ __launch_bounds__(256) void append_part(const int* __restrict__ ei,
    const float* __restrict__ ew, int* __restrict__ bcur,
    int2* __restrict__ bedge, int e) {
  int part = blockIdx.x & 7;
  int grp = blockIdx.x >> 3;
  int ngrp = gridDim.x >> 3;
  for (int i = grp * 256 + threadIdx.x; i < e; i += ngrp * 256) {
    int d = ei[e + i];                 // dst row of edge_index
    int b = d >> 5;
    if ((b & 7) == part) {
      int s = ei[i];
      float w = ew[i];
      int slot = atomicAdd(&bcur[b], 1);
      if (slot < b * BCAP + BCAP)      // overflow guard (never in practice)
        bedge[slot] = make_int2(s | ((d & 31) << 20), __float_as_int(w));
    }
  }
}

__global__ void bucket_count(const int* __restrict__ bcur, int* __restrict__ cntb, int nbk) {
  int i = blockIdx.x * 256 + threadIdx.x;
  if (i < nbk) cntb[i] = min(bcur[i] - i * BCAP, BCAP);
}

// ---------------- scans (over 3125 bucket counts) ----------------
__global__ __launch_bounds__(1024) void scan_block(const int* __restrict__ src,
    int* __restrict__ dst, int* __restrict__ partials, int n) {
  __shared__ int s[1024];
  int t = threadIdx.x;
  int i = blockIdx.x * 1024 + t;
  int v = (i < n) ? src[i] : 0;
  s[t] = v;
  __syncthreads();
  int val = v;
  for (int d = 1; d < 1024; d <<= 1) {
    int other = (t >= d) ? s[t - d] : 0;
    __syncthreads();
    val += other;
    s[t] = val;
    __syncthreads();
  }
  if (i < n) dst[i] = val - v;               // exclusive within block
  if (t == 1023) partials[blockIdx.x] = val; // block total
}

__global__ __launch_bounds__(128) void scan_partials(int* __restrict__ partials, int nb) {
  __shared__ int s[128];
  int t = threadIdx.x;
  int v = (t < nb) ? partials[t] : 0;
  s[t] = v;
  __syncthreads();
  int val = v;
  for (int d = 1; d < 128; d <<= 1) {
    int other = (t >= d) ? s[t - d] : 0;
    __syncthreads();
    val += other;
    s[t] = val;
    __syncthreads();
  }
  if (t < nb) partials[t] = val - v;
}

__global__ void scan_add_b(int* __restrict__ dst, const int* __restrict__ partials, int n) {
  int i = blockIdx.x * 256 + threadIdx.x;
  if (i < n) dst[i] += partials[i >> 10];
}

// ---- per-bucket LDS sort: buckets -> exact CSR (offs, cedge), write-once ----
__global__ __launch_bounds__(256) void bucket2csr(const int* __restrict__ bcur,
    const int2* __restrict__ bedge, const int* __restrict__ bbase,
    int* __restrict__ offs, int2* __restrict__ cedge, int nbk, int n, int e) {
  __shared__ int2 tmp[BCAP];          // 6 KB sorted image
  __shared__ int hist[BSZ], lpref[BSZ], cur[BSZ];
  int t = threadIdx.x;
  int b = blockIdx.x;
  int cnt = min(bcur[b] - b * BCAP, BCAP);
  int base = bbase[b];
  if (t < BSZ) hist[t] = 0;
  __syncthreads();
  for (int i = t; i < cnt; i += 256)
    atomicAdd(&hist[(unsigned)bedge[b * BCAP + i].x >> 20], 1);
  __syncthreads();
  if (t == 0) {
    int a = 0;
    #pragma unroll
    for (int j = 0; j < BSZ; j++) { int v = hist[j]; lpref[j] = a; cur[j] = a; a += v; }
  }
  __syncthreads();
  for (int i = t; i < cnt; i += 256) {
    int2 r = bedge[b * BCAP + i];
    int dl = (unsigned)r.x >> 20;
    int pos = atomicAdd(&cur[dl], 1);
    tmp[pos] = make_int2(r.x & 0xFFFFF, r.y);   // strip dst-local bits
  }
  __syncthreads();
  for (int i = t; i < cnt; i += 256)            // coalesced contiguous flush
    cedge[base + i] = tmp[i];
  if (t < BSZ && b * BSZ + t < n) offs[b * BSZ + t] = base + lpref[t];
  if (b == nbk - 1 && t == 0) offs[n] = base + cnt;
}

// ---------------- weight transpose + fp16 convert ----------------
__global__ void convert_wt(const float* __restrict__ W, _Float16* __restrict__ Wt) {
  int c = blockIdx.x;
  int k = threadIdx.x;
  Wt[c * 128 + k] = (_Float16)W[k * 128 + c];
}

// ------- MFMA GEMM: Y[n,128](f16) = A[n,128] @ W  (Wt = W^T, f16) -------
template<bool A32>
__global__ __launch_bounds__(256) void gemm_f16(const void* __restrict__ Av,
    const _Float16* __restrict__ Wt, _Float16* __restrict__ Y, int n) {
  __shared__ _Float16 Ys[64][136];   // bounce for coalesced stores
  int t = threadIdx.x;
  int wv = t >> 6, l = t & 63;
  int r0 = blockIdx.x * 64 + wv * 16;
  int arow = r0 + (l & 15);
  int kq = (l >> 4) * 8;
  bool rowok = arow < n;
  f32x4 acc[8] = {};
  for (int kc = 0; kc < 128; kc += 32) {
    f16x8 a = {};
    if (rowok) {
      if constexpr (A32) {
        const float* xp = (const float*)Av + (size_t)arow * 128 + kc + kq;
        float4 u0 = *(const float4*)xp;
        float4 u1 = *(const float4*)(xp + 4);
        a[0] = (_Float16)u0.x; a[1] = (_Float16)u0.y;
        a[2] = (_Float16)u0.z; a[3] = (_Float16)u0.w;
        a[4] = (_Float16)u1.x; a[5] = (_Float16)u1.y;
        a[6] = (_Float16)u1.z; a[7] = (_Float16)u1.w;
      } else {
        a = *(const f16x8*)((const _Float16*)Av + (size_t)arow * 128 + kc + kq);
      }
    }
    #pragma unroll
    for (int j = 0; j < 8; j++) {
      f16x8 b = *(const f16x8*)(Wt + (size_t)(j * 16 + (l & 15)) * 128 + kc + kq);
      acc[j] = __builtin_amdgcn_mfma_f32_16x16x32_f16(a, b, acc[j], 0, 0, 0);
    }
  }
  #pragma unroll
  for (int j = 0; j < 8; j++)
    #pragma unroll
    for (int i = 0; i < 4; i++)
      Ys[wv * 16 + (l >> 4) * 4 + i][j * 16 + (l & 15)] = (_Float16)acc[j][i];
  __syncthreads();
  int r = t >> 2;
  int c0 = (t & 3) * 32;
  int grow = blockIdx.x * 64 + r;
  if (grow < n) {
    #pragma unroll
    for (int i = 0; i < 4; i++) {
      f16x8 v = *(const f16x8*)&Ys[r][c0 + i * 8];
      *(f16x8*)(Y + (size_t)grow * 128 + c0 + i * 8) = v;
    }
  }
}

// -- SpMM + self + bias + ReLU (fp16 rows, fp32 reg accum): H = relu(Y + A Y + b) --
__global__ __launch_bounds__(256) void spmm_relu_f16(const _Float16* __restrict__ Y,
    const int* __restrict__ offs, const int2* __restrict__ cedge,
    const float* __restrict__ bias, _Float16* __restrict__ H, int n) {
  int wv = threadIdx.x >> 6;
  int lane = threadIdx.x & 63;
  int node = blockIdx.x * 4 + wv;          // one wave per dst node
  if (node >= n) return;
  int c = lane * 2;                        // 2 channels/lane -> 256B/wave gathers
  const _Float16* Yc = Y + c;
  int e0 = offs[node], e1 = offs[node + 1];
  float ax0 = 0.f, ay0 = 0.f, ax1 = 0.f, ay1 = 0.f;
  float ax2 = 0.f, ay2 = 0.f, ax3 = 0.f, ay3 = 0.f;
  int e = e0;
  for (; e + 3 < e1; e += 4) {             // 4 gathers in flight
    int2 p0 = cedge[e];
    int2 p1 = cedge[e + 1];
    int2 p2 = cedge[e + 2];
    int2 p3 = cedge[e + 3];
    f16x2 v0 = *(const f16x2*)(Yc + (size_t)p0.x * 128);
    f16x2 v1 = *(const f16x2*)(Yc + (size_t)p1.x * 128);
    f16x2 v2 = *(const f16x2*)(Yc + (size_t)p2.x * 128);
    f16x2 v3 = *(const f16x2*)(Yc + (size_t)p3.x * 128);
    float w0 = __int_as_float(p0.y), w1 = __int_as_float(p1.y);
    float w2 = __int_as_float(p2.y), w3 = __int_as_float(p3.y);
    ax0 = fmaf(w0, (float)v0.x, ax0); ay0 = fmaf(w0, (float)v0.y, ay0);
    ax1 = fmaf(w1, (float)v1.x, ax1); ay1 = fmaf(w1, (float)v1.y, ay1);
    ax2 = fmaf(w2, (float)v2.x, ax2); ay2 = fmaf(w2, (float)v2.y, ay2);
    ax3 = fmaf(w3, (float)v3.x, ax3); ay3 = fmaf(w3, (float)v3.y, ay3);
  }
  for (; e < e1; e++) {
    int2 p0 = cedge[e];
    f16x2 v0 = *(const f16x2*)(Yc + (size_t)p0.x * 128);
    float w0 = __int_as_float(p0.y);
    ax0 = fmaf(w0, (float)v0.x, ax0); ay0 = fmaf(w0, (float)v0.y, ay0);
  }
  f16x2 yv = *(const f16x2*)(Yc + (size_t)node * 128);
  float2 bv = *(const float2*)(bias + c);
  float zx = (float)yv.x + (ax0 + ax1) + (ax2 + ax3) + bv.x;
  float zy = (float)yv.y + (ay0 + ay1) + (ay2 + ay3) + bv.y;
  f16x2 o;
  o.x = (_Float16)fmaxf(zx, 0.f);
  o.y = (_Float16)fmaxf(zy, 0.f);
  *(f16x2*)(H + (size_t)node * 128 + c) = o;
}

// -------- FC over concat(h1,h2)(f16) + log_softmax (fp32 compute) --------
__global__ __launch_bounds__(256) void fc_lsm(const _Float16* __restrict__ H1,
    const _Float16* __restrict__ H2, const float* __restrict__ Wfc,
    const float* __restrict__ bfc, float* __restrict__ out, int n) {
  __shared__ float Wl[256 * NCLS];        // 40 KB, [k][c] layout
  __shared__ float Hs[64][132];           // 33 KB, transposed chunk Hs[k][r]
  int t = threadIdx.x;
  for (int i = t; i < 256 * NCLS; i += 256) Wl[i] = Wfc[i];
  int tx = t & 7, ty = t >> 3;            // tx: 5-col group (8x5=40), ty: 4-row group
  int row0 = blockIdx.x * 128;
  float acc[4][5] = {};
  for (int kc = 0; kc < 256; kc += 64) {
    {
      int r = t & 127;
      int half = t >> 7;
      int row = row0 + r;
      const _Float16* src = (kc < 128)
          ? (H1 + (size_t)row * 128 + kc + half * 32)
          : (H2 + (size_t)row * 128 + (kc - 128) + half * 32);
      if (row < n) {
        #pragma unroll
        for (int i = 0; i < 4; i++) {
          f16x8 v = ((const f16x8*)src)[i];
          #pragma unroll
          for (int q = 0; q < 8; q++) Hs[half * 32 + i * 8 + q][r] = (float)v[q];
        }
      } else {
        #pragma unroll
        for (int k = 0; k < 32; k++) Hs[half * 32 + k][r] = 0.f;
      }
    }
    __syncthreads();
    #pragma unroll 4
    for (int k = 0; k < 64; k++) {
      float4 a = *(const float4*)&Hs[k][ty * 4];
      const float* wrow = &Wl[(kc + k) * NCLS + tx * 5];
      float b_[5];
      #pragma unroll
      for (int j = 0; j < 5; j++) b_[j] = wrow[j];
      #pragma unroll
      for (int j = 0; j < 5; j++) {
        acc[0][j] = fmaf(a.x, b_[j], acc[0][j]);
        acc[1][j] = fmaf(a.y, b_[j], acc[1][j]);
        acc[2][j] = fmaf(a.z, b_[j], acc[2][j]);
        acc[3][j] = fmaf(a.w, b_[j], acc[3][j]);
      }
    }
    __syncthreads();
  }
  int c0 = tx * 5;
  float bv[5];
  #pragma unroll
  for (int j = 0; j < 5; j++) bv[j] = bfc[c0 + j];
  #pragma unroll
  for (int i = 0; i < 4; i++) {
    float lg[5];
    #pragma unroll
    for (int j = 0; j < 5; j++) lg[j] = acc[i][j] + bv[j];
    float m = lg[0];
    #pragma unroll
    for (int j = 1; j < 5; j++) m = fmaxf(m, lg[j]);
    m = fmaxf(m, __shfl_xor(m, 1));
    m = fmaxf(m, __shfl_xor(m, 2));
    m = fmaxf(m, __shfl_xor(m, 4));       // 8 lanes (same ty) own one row's 40 cols
    float ssum = 0.f;
    #pragma unroll
    for (int j = 0; j < 5; j++) ssum += __expf(lg[j] - m);
    ssum += __shfl_xor(ssum, 1);
    ssum += __shfl_xor(ssum, 2);
    ssum += __shfl_xor(ssum, 4);
    float lse = m + __logf(ssum);
    int row = row0 + ty * 4 + i;
    if (row < n) {
      #pragma unroll
      for (int j = 0; j < 5; j++) out[(size_t)row * NCLS + c0 + j] = lg[j] - lse;
    }
  }
}

extern "C" void kernel_launch(void* const* d_in, const int* in_sizes, int n_in,
                              void* d_out, int out_size, void* d_ws, size_t ws_size,
                              hipStream_t stream) {
  const float* x   = (const float*)d_in[0];
  const int*   ei  = (const int*)d_in[1];
  const float* ew  = (const float*)d_in[2];
  const float* W1  = (const float*)d_in[3];
  const float* b1  = (const float*)d_in[4];
  const float* W2  = (const float*)d_in[5];
  const float* b2  = (const float*)d_in[6];
  const float* Wfc = (const float*)d_in[7];
  const float* bfc = (const float*)d_in[8];
  float* out = (float*)d_out;
  int n = in_sizes[0] / 128;     // 100000
  int e = in_sizes[2];           // 1600000
  int nbk = (n + BSZ - 1) / BSZ; // 3125 buckets

  // workspace partition (~110 MB)
  char* ws = (char*)d_ws;
  size_t off = 0;
  auto alloc = [&](size_t bytes) -> void* {
    void* p = ws + off; off += (bytes + 255) & ~(size_t)255; return p;
  };
  int*      bcur  = (int*)alloc((size_t)nbk * 4);
  int*      cntb  = (int*)alloc((size_t)nbk * 4);
  int*      bbase = (int*)alloc((size_t)nbk * 4);
  int*      parts = (int*)alloc(1024 * 4);
  int*      offs  = (int*)alloc((size_t)(n + 1) * 4);
  int2*     bedge = (int2*)alloc((size_t)nbk * BCAP * 8);
  int2*     cedge = (int2*)alloc((size_t)e * 8);
  _Float16* w1t   = (_Float16*)alloc(128 * 128 * 2);
  _Float16* w2t   = (_Float16*)alloc(128 * 128 * 2);
  _Float16* y     = (_Float16*)alloc((size_t)n * 128 * 2);
  _Float16* h1    = (_Float16*)alloc((size_t)n * 128 * 2);
  _Float16* h2    = (_Float16*)alloc((size_t)n * 128 * 2);

  int nbb = (nbk + 1023) / 1024;

  // bucketed edge build -> exact CSR
  init_cur<<<(nbk + 255) / 256, 256, 0, stream>>>(bcur, nbk);
  append_part<<<8 * 104, 256, 0, stream>>>(ei, ew, bcur, bedge, e);
  bucket_count<<<(nbk + 255) / 256, 256, 0, stream>>>(bcur, cntb, nbk);
  scan_block<<<nbb, 1024, 0, stream>>>(cntb, bbase, parts, nbk);
  scan_partials<<<1, 128, 0, stream>>>(parts, nbb);
  scan_add_b<<<(nbk + 255) / 256, 256, 0, stream>>>(bbase, parts, nbk);
  bucket2csr<<<nbk, 256, 0, stream>>>(bcur, bedge, bbase, offs, cedge, nbk, n, e);

  // weight converts
  convert_wt<<<128, 128, 0, stream>>>(W1, w1t);
  convert_wt<<<128, 128, 0, stream>>>(W2, w2t);

  int gb = (n + 63) / 64;
  // layer 1: y = x@W1 ; h1 = relu(y + A y + b1)   (x fp32 read fused)
  gemm_f16<true><<<gb, 256, 0, stream>>>((const void*)x, w1t, y, n);
  spmm_relu_f16<<<(n + 3) / 4, 256, 0, stream>>>(y, offs, cedge, b1, h1, n);
  // layer 2: y = h1@W2 ; h2 = relu(y + A y + b2)
  gemm_f16<false><<<gb, 256, 0, stream>>>((const void*)h1, w2t, y, n);
  spmm_relu_f16<<<(n + 3) / 4, 256, 0, stream>>>(y, offs, cedge, b2, h2, n);
  // FC + log_softmax
  fc_lsm<<<(n + 127) / 128, 256, 0, stream>>>(h1, h2, Wfc, bfc, out, n);
}

// Round 7
// 498.473 us; speedup vs baseline: 5.1931x; 1.1381x over previous
//
#include <hip/hip_runtime.h>
#include <math.h>

#define NCLS 40
#define BSZ 32          // dst nodes per bucket
#define BCAP 768        // slots per bucket (avg fill 512, P(overflow) ~ 1e-27)
#define CSTR 16         // cursor stride in ints: 1 counter per 64B line

using f16x8 = __attribute__((ext_vector_type(8))) _Float16;
using f16x2 = __attribute__((ext_vector_type(2))) _Float16;
using f32x4 = __attribute__((ext_vector_type(4))) float;

// ---------------- bucketed edge build ----------------
__global__ void init_cur(int* __restrict__ bcur, int nbk) {
  int i = blockIdx.x * 256 + threadIdx.x;
  if (i < nbk) bcur[i * CSTR] = i * BCAP;
}

// Single-pass append (reads edges ONCE). Cursors are line-padded: R5 showed the
// binder was ~8300 atomic-RMWs serializing on each of ~24 cursor lines, not the
// scattered-write amplification (64MB extra writes = ~10us HBM, acceptable).
__global__ __launch_bounds__(256) void append_one(const int* __restrict__ ei,
    const float* __restrict__ ew, int* __restrict__ bcur,
    int2* __restrict__ bedge, int e) {
  int i = blockIdx.x * 256 + threadIdx.x;
  if (i >= e) return;
  int d = ei[e + i];                 // dst row of edge_index
  int s = ei[i];
  float w = ew[i];
  int b = d >> 5;
  int slot = atomicAdd(&bcur[b * CSTR], 1);
  if (slot < b * BCAP + BCAP)        // overflow guard (never in practice)
    bedge[slot] = make_int2(s | ((d & 31) << 20), __float_as_int(w));
}

__global__ void bucket_count(const int* __restrict__ bcur, int* __restrict__ cntb, int nbk) {
  int i = blockIdx.x * 256 + threadIdx.x;
  if (i < nbk) cntb[i] = min(bcur[i * CSTR] - i * BCAP, BCAP);
}

// ---------------- scans (over 3125 bucket counts) ----------------
__global__ __launch_bounds__(1024) void scan_block(const int* __restrict__ src,
    int* __restrict__ dst, int* __restrict__ partials, int n) {
  __shared__ int s[1024];
  int t = threadIdx.x;
  int i = blockIdx.x * 1024 + t;
  int v = (i < n) ? src[i] : 0;
  s[t] = v;
  __syncthreads();
  int val = v;
  for (int d = 1; d < 1024; d <<= 1) {
    int other = (t >= d) ? s[t - d] : 0;
    __syncthreads();
    val += other;
    s[t] = val;
    __syncthreads();
  }
  if (i < n) dst[i] = val - v;               // exclusive within block
  if (t == 1023) partials[blockIdx.x] = val; // block total
}

__global__ __launch_bounds__(128) void scan_partials(int* __restrict__ partials, int nb) {
  __shared__ int s[128];
  int t = threadIdx.x;
  int v = (t < nb) ? partials[t] : 0;
  s[t] = v;
  __syncthreads();
  int val = v;
  for (int d = 1; d < 128; d <<= 1) {
    int other = (t >= d) ? s[t - d] : 0;
    __syncthreads();
    val += other;
    s[t] = val;
    __syncthreads();
  }
  if (t < nb) partials[t] = val - v;
}

__global__ void scan_add_b(int* __restrict__ dst, const int* __restrict__ partials, int n) {
  int i = blockIdx.x * 256 + threadIdx.x;
  if (i < n) dst[i] += partials[i >> 10];
}

// ---- per-bucket LDS sort: buckets -> exact CSR (offs, cedge), write-once ----
__global__ __launch_bounds__(256) void bucket2csr(const int* __restrict__ bcur,
    const int2* __restrict__ bedge, const int* __restrict__ bbase,
    int* __restrict__ offs, int2* __restrict__ cedge, int nbk, int n, int e) {
  __shared__ int2 tmp[BCAP];          // 6 KB sorted image
  __shared__ int hist[BSZ], lpref[BSZ], cur[BSZ];
  int t = threadIdx.x;
  int b = blockIdx.x;
  int cnt = min(bcur[b * CSTR] - b * BCAP, BCAP);
  int base = bbase[b];
  if (t < BSZ) hist[t] = 0;
  __syncthreads();
  for (int i = t; i < cnt; i += 256)
    atomicAdd(&hist[(unsigned)bedge[b * BCAP + i].x >> 20], 1);
  __syncthreads();
  if (t == 0) {
    int a = 0;
    #pragma unroll
    for (int j = 0; j < BSZ; j++) { int v = hist[j]; lpref[j] = a; cur[j] = a; a += v; }
  }
  __syncthreads();
  for (int i = t; i < cnt; i += 256) {
    int2 r = bedge[b * BCAP + i];
    int dl = (unsigned)r.x >> 20;
    int pos = atomicAdd(&cur[dl], 1);
    tmp[pos] = make_int2(r.x & 0xFFFFF, r.y);   // strip dst-local bits
  }
  __syncthreads();
  for (int i = t; i < cnt; i += 256)            // coalesced contiguous flush
    cedge[base + i] = tmp[i];
  if (t < BSZ && b * BSZ + t < n) offs[b * BSZ + t] = base + lpref[t];
  if (b == nbk - 1 && t == 0) offs[n] = base + cnt;
}

// ---------------- weight transpose + fp16 convert ----------------
__global__ void convert_wt(const float* __restrict__ W, _Float16* __restrict__ Wt) {
  int c = blockIdx.x;
  int k = threadIdx.x;
  Wt[c * 128 + k] = (_Float16)W[k * 128 + c];
}

// ------- MFMA GEMM: Y[n,128](f16) = A[n,128] @ W  (Wt = W^T, f16) -------
template<bool A32>
__global__ __launch_bounds__(256) void gemm_f16(const void* __restrict__ Av,
    const _Float16* __restrict__ Wt, _Float16* __restrict__ Y, int n) {
  __shared__ _Float16 Ys[64][136];   // bounce for coalesced stores
  int t = threadIdx.x;
  int wv = t >> 6, l = t & 63;
  int r0 = blockIdx.x * 64 + wv * 16;
  int arow = r0 + (l & 15);
  int kq = (l >> 4) * 8;
  bool rowok = arow < n;
  f32x4 acc[8] = {};
  for (int kc = 0; kc < 128; kc += 32) {
    f16x8 a = {};
    if (rowok) {
      if constexpr (A32) {
        const float* xp = (const float*)Av + (size_t)arow * 128 + kc + kq;
        float4 u0 = *(const float4*)xp;
        float4 u1 = *(const float4*)(xp + 4);
        a[0] = (_Float16)u0.x; a[1] = (_Float16)u0.y;
        a[2] = (_Float16)u0.z; a[3] = (_Float16)u0.w;
        a[4] = (_Float16)u1.x; a[5] = (_Float16)u1.y;
        a[6] = (_Float16)u1.z; a[7] = (_Float16)u1.w;
      } else {
        a = *(const f16x8*)((const _Float16*)Av + (size_t)arow * 128 + kc + kq);
      }
    }
    #pragma unroll
    for (int j = 0; j < 8; j++) {
      f16x8 b = *(const f16x8*)(Wt + (size_t)(j * 16 + (l & 15)) * 128 + kc + kq);
      acc[j] = __builtin_amdgcn_mfma_f32_16x16x32_f16(a, b, acc[j], 0, 0, 0);
    }
  }
  #pragma unroll
  for (int j = 0; j < 8; j++)
    #pragma unroll
    for (int i = 0; i < 4; i++)
      Ys[wv * 16 + (l >> 4) * 4 + i][j * 16 + (l & 15)] = (_Float16)acc[j][i];
  __syncthreads();
  int r = t >> 2;
  int c0 = (t & 3) * 32;
  int grow = blockIdx.x * 64 + r;
  if (grow < n) {
    #pragma unroll
    for (int i = 0; i < 4; i++) {
      f16x8 v = *(const f16x8*)&Ys[r][c0 + i * 8];
      *(f16x8*)(Y + (size_t)grow * 128 + c0 + i * 8) = v;
    }
  }
}

// -- SpMM + self + bias + ReLU (fp16 rows, fp32 reg accum): H = relu(Y + A Y + b) --
__global__ __launch_bounds__(256) void spmm_relu_f16(const _Float16* __restrict__ Y,
    const int* __restrict__ offs, const int2* __restrict__ cedge,
    const float* __restrict__ bias, _Float16* __restrict__ H, int n) {
  int wv = threadIdx.x >> 6;
  int lane = threadIdx.x & 63;
  int node = blockIdx.x * 4 + wv;          // one wave per dst node
  if (node >= n) return;
  int c = lane * 2;                        // 2 channels/lane -> 256B/wave gathers
  const _Float16* Yc = Y + c;
  int e0 = offs[node], e1 = offs[node + 1];
  float ax0 = 0.f, ay0 = 0.f, ax1 = 0.f, ay1 = 0.f;
  float ax2 = 0.f, ay2 = 0.f, ax3 = 0.f, ay3 = 0.f;
  int e = e0;
  for (; e + 3 < e1; e += 4) {             // 4 gathers in flight
    int2 p0 = cedge[e];
    int2 p1 = cedge[e + 1];
    int2 p2 = cedge[e + 2];
    int2 p3 = cedge[e + 3];
    f16x2 v0 = *(const f16x2*)(Yc + (size_t)p0.x * 128);
    f16x2 v1 = *(const f16x2*)(Yc + (size_t)p1.x * 128);
    f16x2 v2 = *(const f16x2*)(Yc + (size_t)p2.x * 128);
    f16x2 v3 = *(const f16x2*)(Yc + (size_t)p3.x * 128);
    float w0 = __int_as_float(p0.y), w1 = __int_as_float(p1.y);
    float w2 = __int_as_float(p2.y), w3 = __int_as_float(p3.y);
    ax0 = fmaf(w0, (float)v0.x, ax0); ay0 = fmaf(w0, (float)v0.y, ay0);
    ax1 = fmaf(w1, (float)v1.x, ax1); ay1 = fmaf(w1, (float)v1.y, ay1);
    ax2 = fmaf(w2, (float)v2.x, ax2); ay2 = fmaf(w2, (float)v2.y, ay2);
    ax3 = fmaf(w3, (float)v3.x, ax3); ay3 = fmaf(w3, (float)v3.y, ay3);
  }
  for (; e < e1; e++) {
    int2 p0 = cedge[e];
    f16x2 v0 = *(const f16x2*)(Yc + (size_t)p0.x * 128);
    float w0 = __int_as_float(p0.y);
    ax0 = fmaf(w0, (float)v0.x, ax0); ay0 = fmaf(w0, (float)v0.y, ay0);
  }
  f16x2 yv = *(const f16x2*)(Yc + (size_t)node * 128);
  float2 bv = *(const float2*)(bias + c);
  float zx = (float)yv.x + (ax0 + ax1) + (ax2 + ax3) + bv.x;
  float zy = (float)yv.y + (ay0 + ay1) + (ay2 + ay3) + bv.y;
  f16x2 o;
  o.x = (_Float16)fmaxf(zx, 0.f);
  o.y = (_Float16)fmaxf(zy, 0.f);
  *(f16x2*)(H + (size_t)node * 128 + c) = o;
}

// -------- FC over concat(h1,h2)(f16) + log_softmax (fp32 compute) --------
__global__ __launch_bounds__(256) void fc_lsm(const _Float16* __restrict__ H1,
    const _Float16* __restrict__ H2, const float* __restrict__ Wfc,
    const float* __restrict__ bfc, float* __restrict__ out, int n) {
  __shared__ float Wl[256 * NCLS];        // 40 KB, [k][c] layout
  __shared__ float Hs[64][132];           // 33 KB, transposed chunk Hs[k][r]
  int t = threadIdx.x;
  for (int i = t; i < 256 * NCLS; i += 256) Wl[i] = Wfc[i];
  int tx = t & 7, ty = t >> 3;            // tx: 5-col group (8x5=40), ty: 4-row group
  int row0 = blockIdx.x * 128;
  float acc[4][5] = {};
  for (int kc = 0; kc < 256; kc += 64) {
    {
      int r = t & 127;
      int half = t >> 7;
      int row = row0 + r;
      const _Float16* src = (kc < 128)
          ? (H1 + (size_t)row * 128 + kc + half * 32)
          : (H2 + (size_t)row * 128 + (kc - 128) + half * 32);
      if (row < n) {
        #pragma unroll
        for (int i = 0; i < 4; i++) {
          f16x8 v = ((const f16x8*)src)[i];
          #pragma unroll
          for (int q = 0; q < 8; q++) Hs[half * 32 + i * 8 + q][r] = (float)v[q];
        }
      } else {
        #pragma unroll
        for (int k = 0; k < 32; k++) Hs[half * 32 + k][r] = 0.f;
      }
    }
    __syncthreads();
    #pragma unroll 4
    for (int k = 0; k < 64; k++) {
      float4 a = *(const float4*)&Hs[k][ty * 4];
      const float* wrow = &Wl[(kc + k) * NCLS + tx * 5];
      float b_[5];
      #pragma unroll
      for (int j = 0; j < 5; j++) b_[j] = wrow[j];
      #pragma unroll
      for (int j = 0; j < 5; j++) {
        acc[0][j] = fmaf(a.x, b_[j], acc[0][j]);
        acc[1][j] = fmaf(a.y, b_[j], acc[1][j]);
        acc[2][j] = fmaf(a.z, b_[j], acc[2][j]);
        acc[3][j] = fmaf(a.w, b_[j], acc[3][j]);
      }
    }
    __syncthreads();
  }
  int c0 = tx * 5;
  float bv[5];
  #pragma unroll
  for (int j = 0; j < 5; j++) bv[j] = bfc[c0 + j];
  #pragma unroll
  for (int i = 0; i < 4; i++) {
    float lg[5];
    #pragma unroll
    for (int j = 0; j < 5; j++) lg[j] = acc[i][j] + bv[j];
    float m = lg[0];
    #pragma unroll
    for (int j = 1; j < 5; j++) m = fmaxf(m, lg[j]);
    m = fmaxf(m, __shfl_xor(m, 1));
    m = fmaxf(m, __shfl_xor(m, 2));
    m = fmaxf(m, __shfl_xor(m, 4));       // 8 lanes (same ty) own one row's 40 cols
    float ssum = 0.f;
    #pragma unroll
    for (int j = 0; j < 5; j++) ssum += __expf(lg[j] - m);
    ssum += __shfl_xor(ssum, 1);
    ssum += __shfl_xor(ssum, 2);
    ssum += __shfl_xor(ssum, 4);
    float lse = m + __logf(ssum);
    int row = row0 + ty * 4 + i;
    if (row < n) {
      #pragma unroll
      for (int j = 0; j < 5; j++) out[(size_t)row * NCLS + c0 + j] = lg[j] - lse;
    }
  }
}

extern "C" void kernel_launch(void* const* d_in, const int* in_sizes, int n_in,
                              void* d_out, int out_size, void* d_ws, size_t ws_size,
                              hipStream_t stream) {
  const float* x   = (const float*)d_in[0];
  const int*   ei  = (const int*)d_in[1];
  const float* ew  = (const float*)d_in[2];
  const float* W1  = (const float*)d_in[3];
  const float* b1  = (const float*)d_in[4];
  const float* W2  = (const float*)d_in[5];
  const float* b2  = (const float*)d_in[6];
  const float* Wfc = (const float*)d_in[7];
  const float* bfc = (const float*)d_in[8];
  float* out = (float*)d_out;
  int n = in_sizes[0] / 128;     // 100000
  int e = in_sizes[2];           // 1600000
  int nbk = (n + BSZ - 1) / BSZ; // 3125 buckets

  // workspace partition (~110 MB)
  char* ws = (char*)d_ws;
  size_t off = 0;
  auto alloc = [&](size_t bytes) -> void* {
    void* p = ws + off; off += (bytes + 255) & ~(size_t)255; return p;
  };
  int*      bcur  = (int*)alloc((size_t)nbk * CSTR * 4);  // line-padded cursors
  int*      cntb  = (int*)alloc((size_t)nbk * 4);
  int*      bbase = (int*)alloc((size_t)nbk * 4);
  int*      parts = (int*)alloc(1024 * 4);
  int*      offs  = (int*)alloc((size_t)(n + 1) * 4);
  int2*     bedge = (int2*)alloc((size_t)nbk * BCAP * 8);
  int2*     cedge = (int2*)alloc((size_t)e * 8);
  _Float16* w1t   = (_Float16*)alloc(128 * 128 * 2);
  _Float16* w2t   = (_Float16*)alloc(128 * 128 * 2);
  _Float16* y     = (_Float16*)alloc((size_t)n * 128 * 2);
  _Float16* h1    = (_Float16*)alloc((size_t)n * 128 * 2);
  _Float16* h2    = (_Float16*)alloc((size_t)n * 128 * 2);

  int nbb = (nbk + 1023) / 1024;

  // bucketed edge build -> exact CSR
  init_cur<<<(nbk + 255) / 256, 256, 0, stream>>>(bcur, nbk);
  append_one<<<(e + 255) / 256, 256, 0, stream>>>(ei, ew, bcur, bedge, e);
  bucket_count<<<(nbk + 255) / 256, 256, 0, stream>>>(bcur, cntb, nbk);
  scan_block<<<nbb, 1024, 0, stream>>>(cntb, bbase, parts, nbk);
  scan_partials<<<1, 128, 0, stream>>>(parts, nbb);
  scan_add_b<<<(nbk + 255) / 256, 256, 0, stream>>>(bbase, parts, nbk);
  bucket2csr<<<nbk, 256, 0, stream>>>(bcur, bedge, bbase, offs, cedge, nbk, n, e);

  // weight converts
  convert_wt<<<128, 128, 0, stream>>>(W1, w1t);
  convert_wt<<<128, 128, 0, stream>>>(W2, w2t);

  int gb = (n + 63) / 64;
  // layer 1: y = x@W1 ; h1 = relu(y + A y + b1)   (x fp32 read fused)
  gemm_f16<true><<<gb, 256, 0, stream>>>((const void*)x, w1t, y, n);
  spmm_relu_f16<<<(n + 3) / 4, 256, 0, stream>>>(y, offs, cedge, b1, h1, n);
  // layer 2: y = h1@W2 ; h2 = relu(y + A y + b2)
  gemm_f16<false><<<gb, 256, 0, stream>>>((const void*)h1, w2t, y, n);
  spmm_relu_f16<<<(n + 3) / 4, 256, 0, stream>>>(y, offs, cedge, b2, h2, n);
  // FC + log_softmax
  fc_lsm<<<(n + 127) / 128, 256, 0, stream>>>(h1, h2, Wfc, bfc, out, n);
}

// Round 8
// 492.522 us; speedup vs baseline: 5.2559x; 1.0121x over previous
//
#include <hip/hip_runtime.h>
#include <math.h>

#define NCLS 40
#define BSZ 32          // dst nodes per bucket
#define BCAP 768        // slots per bucket (avg fill 512, P(overflow) ~ 1e-27)
#define CSTR 16         // cursor stride in ints: 1 counter per 64B line

using f16x8 = __attribute__((ext_vector_type(8))) _Float16;
using f16x2 = __attribute__((ext_vector_type(2))) _Float16;
using f32x4 = __attribute__((ext_vector_type(4))) float;

// ---------------- bucketed edge build ----------------
__global__ void init_cur(int* __restrict__ bcur, int nbk) {
  int i = blockIdx.x * 256 + threadIdx.x;
  if (i < nbk) bcur[i * CSTR] = i * BCAP;
}

// Partitioned append: (bucket&7)==blockIdx&7 matches the round-robin block->XCD
// dispatch, so each bucket's 6KB bedge region is written by ONE XCD only.
// R3/R5/R7 post-mortem: scattered 8B writes shared by ~8 non-coherent XCD L2s
// cause ~8 partial-line HBM writebacks each (~92MB at ~950GB/s = the 108us).
// Cursors stay line-padded (R7 fix: kills the ~8300-RMW/line serialization).
__global__ __launch_bounds__(256) void append_part(const int* __restrict__ ei,
    const float* __restrict__ ew, int* __restrict__ bcur,
    int2* __restrict__ bedge, int e) {
  int part = blockIdx.x & 7;
  int grp = blockIdx.x >> 3;
  int ngrp = gridDim.x >> 3;
  for (int i = grp * 256 + threadIdx.x; i < e; i += ngrp * 256) {
    int d = ei[e + i];                 // dst row of edge_index
    int b = d >> 5;
    if ((b & 7) == part) {
      int slot = atomicAdd(&bcur[b * CSTR], 1);
      if (slot < b * BCAP + BCAP)      // overflow guard (never in practice)
        bedge[slot] = make_int2(ei[i] | ((d & 31) << 20), __float_as_int(ew[i]));
    }
  }
}

__global__ void bucket_count(const int* __restrict__ bcur, int* __restrict__ cntb, int nbk) {
  int i = blockIdx.x * 256 + threadIdx.x;
  if (i < nbk) cntb[i] = min(bcur[i * CSTR] - i * BCAP, BCAP);
}

// ---------------- scans (over 3125 bucket counts) ----------------
__global__ __launch_bounds__(1024) void scan_block(const int* __restrict__ src,
    int* __restrict__ dst, int* __restrict__ partials, int n) {
  __shared__ int s[1024];
  int t = threadIdx.x;
  int i = blockIdx.x * 1024 + t;
  int v = (i < n) ? src[i] : 0;
  s[t] = v;
  __syncthreads();
  int val = v;
  for (int d = 1; d < 1024; d <<= 1) {
    int other = (t >= d) ? s[t - d] : 0;
    __syncthreads();
    val += other;
    s[t] = val;
    __syncthreads();
  }
  if (i < n) dst[i] = val - v;               // exclusive within block
  if (t == 1023) partials[blockIdx.x] = val; // block total
}

__global__ __launch_bounds__(128) void scan_partials(int* __restrict__ partials, int nb) {
  __shared__ int s[128];
  int t = threadIdx.x;
  int v = (t < nb) ? partials[t] : 0;
  s[t] = v;
  __syncthreads();
  int val = v;
  for (int d = 1; d < 128; d <<= 1) {
    int other = (t >= d) ? s[t - d] : 0;
    __syncthreads();
    val += other;
    s[t] = val;
    __syncthreads();
  }
  if (t < nb) partials[t] = val - v;
}

__global__ void scan_add_b(int* __restrict__ dst, const int* __restrict__ partials, int n) {
  int i = blockIdx.x * 256 + threadIdx.x;
  if (i < n) dst[i] += partials[i >> 10];
}

// ---- per-bucket LDS sort: buckets -> exact CSR (offs, cedge), write-once ----
__global__ __launch_bounds__(256) void bucket2csr(const int* __restrict__ bcur,
    const int2* __restrict__ bedge, const int* __restrict__ bbase,
    int* __restrict__ offs, int2* __restrict__ cedge, int nbk, int n, int e) {
  __shared__ int2 tmp[BCAP];          // 6 KB sorted image
  __shared__ int hist[BSZ], lpref[BSZ], cur[BSZ];
  int t = threadIdx.x;
  int b = blockIdx.x;
  int cnt = min(bcur[b * CSTR] - b * BCAP, BCAP);
  int base = bbase[b];
  if (t < BSZ) hist[t] = 0;
  __syncthreads();
  for (int i = t; i < cnt; i += 256)
    atomicAdd(&hist[(unsigned)bedge[b * BCAP + i].x >> 20], 1);
  __syncthreads();
  if (t == 0) {
    int a = 0;
    #pragma unroll
    for (int j = 0; j < BSZ; j++) { int v = hist[j]; lpref[j] = a; cur[j] = a; a += v; }
  }
  __syncthreads();
  for (int i = t; i < cnt; i += 256) {
    int2 r = bedge[b * BCAP + i];
    int dl = (unsigned)r.x >> 20;
    int pos = atomicAdd(&cur[dl], 1);
    tmp[pos] = make_int2(r.x & 0xFFFFF, r.y);   // strip dst-local bits
  }
  __syncthreads();
  for (int i = t; i < cnt; i += 256)            // coalesced contiguous flush
    cedge[base + i] = tmp[i];
  if (t < BSZ && b * BSZ + t < n) offs[b * BSZ + t] = base + lpref[t];
  if (b == nbk - 1 && t == 0) offs[n] = base + cnt;
}

// ---------------- weight transpose + fp16 convert ----------------
__global__ void convert_wt(const float* __restrict__ W, _Float16* __restrict__ Wt) {
  int c = blockIdx.x;
  int k = threadIdx.x;
  Wt[c * 128 + k] = (_Float16)W[k * 128 + c];
}

// ------- MFMA GEMM: Y[n,128](f16) = A[n,128] @ W  (Wt = W^T, f16) -------
template<bool A32>
__global__ __launch_bounds__(256) void gemm_f16(const void* __restrict__ Av,
    const _Float16* __restrict__ Wt, _Float16* __restrict__ Y, int n) {
  __shared__ _Float16 Ys[64][136];   // bounce for coalesced stores
  int t = threadIdx.x;
  int wv = t >> 6, l = t & 63;
  int r0 = blockIdx.x * 64 + wv * 16;
  int arow = r0 + (l & 15);
  int kq = (l >> 4) * 8;
  bool rowok = arow < n;
  f32x4 acc[8] = {};
  for (int kc = 0; kc < 128; kc += 32) {
    f16x8 a = {};
    if (rowok) {
      if constexpr (A32) {
        const float* xp = (const float*)Av + (size_t)arow * 128 + kc + kq;
        float4 u0 = *(const float4*)xp;
        float4 u1 = *(const float4*)(xp + 4);
        a[0] = (_Float16)u0.x; a[1] = (_Float16)u0.y;
        a[2] = (_Float16)u0.z; a[3] = (_Float16)u0.w;
        a[4] = (_Float16)u1.x; a[5] = (_Float16)u1.y;
        a[6] = (_Float16)u1.z; a[7] = (_Float16)u1.w;
      } else {
        a = *(const f16x8*)((const _Float16*)Av + (size_t)arow * 128 + kc + kq);
      }
    }
    #pragma unroll
    for (int j = 0; j < 8; j++) {
      f16x8 b = *(const f16x8*)(Wt + (size_t)(j * 16 + (l & 15)) * 128 + kc + kq);
      acc[j] = __builtin_amdgcn_mfma_f32_16x16x32_f16(a, b, acc[j], 0, 0, 0);
    }
  }
  #pragma unroll
  for (int j = 0; j < 8; j++)
    #pragma unroll
    for (int i = 0; i < 4; i++)
      Ys[wv * 16 + (l >> 4) * 4 + i][j * 16 + (l & 15)] = (_Float16)acc[j][i];
  __syncthreads();
  int r = t >> 2;
  int c0 = (t & 3) * 32;
  int grow = blockIdx.x * 64 + r;
  if (grow < n) {
    #pragma unroll
    for (int i = 0; i < 4; i++) {
      f16x8 v = *(const f16x8*)&Ys[r][c0 + i * 8];
      *(f16x8*)(Y + (size_t)grow * 128 + c0 + i * 8) = v;
    }
  }
}

// -- SpMM + self + bias + ReLU (fp16 rows, fp32 reg accum): H = relu(Y + A Y + b) --
__global__ __launch_bounds__(256) void spmm_relu_f16(const _Float16* __restrict__ Y,
    const int* __restrict__ offs, const int2* __restrict__ cedge,
    const float* __restrict__ bias, _Float16* __restrict__ H, int n) {
  int wv = threadIdx.x >> 6;
  int lane = threadIdx.x & 63;
  int node = blockIdx.x * 4 + wv;          // one wave per dst node
  if (node >= n) return;
  int c = lane * 2;                        // 2 channels/lane -> 256B/wave gathers
  const _Float16* Yc = Y + c;
  int e0 = offs[node], e1 = offs[node + 1];
  float ax0 = 0.f, ay0 = 0.f, ax1 = 0.f, ay1 = 0.f;
  float ax2 = 0.f, ay2 = 0.f, ax3 = 0.f, ay3 = 0.f;
  int e = e0;
  for (; e + 3 < e1; e += 4) {             // 4 gathers in flight
    int2 p0 = cedge[e];
    int2 p1 = cedge[e + 1];
    int2 p2 = cedge[e + 2];
    int2 p3 = cedge[e + 3];
    f16x2 v0 = *(const f16x2*)(Yc + (size_t)p0.x * 128);
    f16x2 v1 = *(const f16x2*)(Yc + (size_t)p1.x * 128);
    f16x2 v2 = *(const f16x2*)(Yc + (size_t)p2.x * 128);
    f16x2 v3 = *(const f16x2*)(Yc + (size_t)p3.x * 128);
    float w0 = __int_as_float(p0.y), w1 = __int_as_float(p1.y);
    float w2 = __int_as_float(p2.y), w3 = __int_as_float(p3.y);
    ax0 = fmaf(w0, (float)v0.x, ax0); ay0 = fmaf(w0, (float)v0.y, ay0);
    ax1 = fmaf(w1, (float)v1.x, ax1); ay1 = fmaf(w1, (float)v1.y, ay1);
    ax2 = fmaf(w2, (float)v2.x, ax2); ay2 = fmaf(w2, (float)v2.y, ay2);
    ax3 = fmaf(w3, (float)v3.x, ax3); ay3 = fmaf(w3, (float)v3.y, ay3);
  }
  for (; e < e1; e++) {
    int2 p0 = cedge[e];
    f16x2 v0 = *(const f16x2*)(Yc + (size_t)p0.x * 128);
    float w0 = __int_as_float(p0.y);
    ax0 = fmaf(w0, (float)v0.x, ax0); ay0 = fmaf(w0, (float)v0.y, ay0);
  }
  f16x2 yv = *(const f16x2*)(Yc + (size_t)node * 128);
  float2 bv = *(const float2*)(bias + c);
  float zx = (float)yv.x + (ax0 + ax1) + (ax2 + ax3) + bv.x;
  float zy = (float)yv.y + (ay0 + ay1) + (ay2 + ay3) + bv.y;
  f16x2 o;
  o.x = (_Float16)fmaxf(zx, 0.f);
  o.y = (_Float16)fmaxf(zy, 0.f);
  *(f16x2*)(H + (size_t)node * 128 + c) = o;
}

// -------- FC over concat(h1,h2)(f16) + log_softmax (fp32 compute) --------
__global__ __launch_bounds__(256) void fc_lsm(const _Float16* __restrict__ H1,
    const _Float16* __restrict__ H2, const float* __restrict__ Wfc,
    const float* __restrict__ bfc, float* __restrict__ out, int n) {
  __shared__ float Wl[256 * NCLS];        // 40 KB, [k][c] layout
  __shared__ float Hs[64][132];           // 33 KB, transposed chunk Hs[k][r]
  int t = threadIdx.x;
  for (int i = t; i < 256 * NCLS; i += 256) Wl[i] = Wfc[i];
  int tx = t & 7, ty = t >> 3;            // tx: 5-col group (8x5=40), ty: 4-row group
  int row0 = blockIdx.x * 128;
  float acc[4][5] = {};
  for (int kc = 0; kc < 256; kc += 64) {
    {
      int r = t & 127;
      int half = t >> 7;
      int row = row0 + r;
      const _Float16* src = (kc < 128)
          ? (H1 + (size_t)row * 128 + kc + half * 32)
          : (H2 + (size_t)row * 128 + (kc - 128) + half * 32);
      if (row < n) {
        #pragma unroll
        for (int i = 0; i < 4; i++) {
          f16x8 v = ((const f16x8*)src)[i];
          #pragma unroll
          for (int q = 0; q < 8; q++) Hs[half * 32 + i * 8 + q][r] = (float)v[q];
        }
      } else {
        #pragma unroll
        for (int k = 0; k < 32; k++) Hs[half * 32 + k][r] = 0.f;
      }
    }
    __syncthreads();
    #pragma unroll 4
    for (int k = 0; k < 64; k++) {
      float4 a = *(const float4*)&Hs[k][ty * 4];
      const float* wrow = &Wl[(kc + k) * NCLS + tx * 5];
      float b_[5];
      #pragma unroll
      for (int j = 0; j < 5; j++) b_[j] = wrow[j];
      #pragma unroll
      for (int j = 0; j < 5; j++) {
        acc[0][j] = fmaf(a.x, b_[j], acc[0][j]);
        acc[1][j] = fmaf(a.y, b_[j], acc[1][j]);
        acc[2][j] = fmaf(a.z, b_[j], acc[2][j]);
        acc[3][j] = fmaf(a.w, b_[j], acc[3][j]);
      }
    }
    __syncthreads();
  }
  int c0 = tx * 5;
  float bv[5];
  #pragma unroll
  for (int j = 0; j < 5; j++) bv[j] = bfc[c0 + j];
  #pragma unroll
  for (int i = 0; i < 4; i++) {
    float lg[5];
    #pragma unroll
    for (int j = 0; j < 5; j++) lg[j] = acc[i][j] + bv[j];
    float m = lg[0];
    #pragma unroll
    for (int j = 1; j < 5; j++) m = fmaxf(m, lg[j]);
    m = fmaxf(m, __shfl_xor(m, 1));
    m = fmaxf(m, __shfl_xor(m, 2));
    m = fmaxf(m, __shfl_xor(m, 4));       // 8 lanes (same ty) own one row's 40 cols
    float ssum = 0.f;
    #pragma unroll
    for (int j = 0; j < 5; j++) ssum += __expf(lg[j] - m);
    ssum += __shfl_xor(ssum, 1);
    ssum += __shfl_xor(ssum, 2);
    ssum += __shfl_xor(ssum, 4);
    float lse = m + __logf(ssum);
    int row = row0 + ty * 4 + i;
    if (row < n) {
      #pragma unroll
      for (int j = 0; j < 5; j++) out[(size_t)row * NCLS + c0 + j] = lg[j] - lse;
    }
  }
}

extern "C" void kernel_launch(void* const* d_in, const int* in_sizes, int n_in,
                              void* d_out, int out_size, void* d_ws, size_t ws_size,
                              hipStream_t stream) {
  const float* x   = (const float*)d_in[0];
  const int*   ei  = (const int*)d_in[1];
  const float* ew  = (const float*)d_in[2];
  const float* W1  = (const float*)d_in[3];
  const float* b1  = (const float*)d_in[4];
  const float* W2  = (const float*)d_in[5];
  const float* b2  = (const float*)d_in[6];
  const float* Wfc = (const float*)d_in[7];
  const float* bfc = (const float*)d_in[8];
  float* out = (float*)d_out;
  int n = in_sizes[0] / 128;     // 100000
  int e = in_sizes[2];           // 1600000
  int nbk = (n + BSZ - 1) / BSZ; // 3125 buckets

  // workspace partition (~110 MB)
  char* ws = (char*)d_ws;
  size_t off = 0;
  auto alloc = [&](size_t bytes) -> void* {
    void* p = ws + off; off += (bytes + 255) & ~(size_t)255; return p;
  };
  int*      bcur  = (int*)alloc((size_t)nbk * CSTR * 4);  // line-padded cursors
  int*      cntb  = (int*)alloc((size_t)nbk * 4);
  int*      bbase = (int*)alloc((size_t)nbk * 4);
  int*      parts = (int*)alloc(1024 * 4);
  int*      offs  = (int*)alloc((size_t)(n + 1) * 4);
  int2*     bedge = (int2*)alloc((size_t)nbk * BCAP * 8);
  int2*     cedge = (int2*)alloc((size_t)e * 8);
  _Float16* w1t   = (_Float16*)alloc(128 * 128 * 2);
  _Float16* w2t   = (_Float16*)alloc(128 * 128 * 2);
  _Float16* y     = (_Float16*)alloc((size_t)n * 128 * 2);
  _Float16* h1    = (_Float16*)alloc((size_t)n * 128 * 2);
  _Float16* h2    = (_Float16*)alloc((size_t)n * 128 * 2);

  int nbb = (nbk + 1023) / 1024;

  // bucketed edge build -> exact CSR
  init_cur<<<(nbk + 255) / 256, 256, 0, stream>>>(bcur, nbk);
  append_part<<<8 * 104, 256, 0, stream>>>(ei, ew, bcur, bedge, e);
  bucket_count<<<(nbk + 255) / 256, 256, 0, stream>>>(bcur, cntb, nbk);
  scan_block<<<nbb, 1024, 0, stream>>>(cntb, bbase, parts, nbk);
  scan_partials<<<1, 128, 0, stream>>>(parts, nbb);
  scan_add_b<<<(nbk + 255) / 256, 256, 0, stream>>>(bbase, parts, nbk);
  bucket2csr<<<nbk, 256, 0, stream>>>(bcur, bedge, bbase, offs, cedge, nbk, n, e);

  // weight converts
  convert_wt<<<128, 128, 0, stream>>>(W1, w1t);
  convert_wt<<<128, 128, 0, stream>>>(W2, w2t);

  int gb = (n + 63) / 64;
  // layer 1: y = x@W1 ; h1 = relu(y + A y + b1)   (x fp32 read fused)
  gemm_f16<true><<<gb, 256, 0, stream>>>((const void*)x, w1t, y, n);
  spmm_relu_f16<<<(n + 3) / 4, 256, 0, stream>>>(y, offs, cedge, b1, h1, n);
  // layer 2: y = h1@W2 ; h2 = relu(y + A y + b2)
  gemm_f16<false><<<gb, 256, 0, stream>>>((const void*)h1, w2t, y, n);
  spmm_relu_f16<<<(n + 3) / 4, 256, 0, stream>>>(y, offs, cedge, b2, h2, n);
  // FC + log_softmax
  fc_lsm<<<(n + 127) / 128, 256, 0, stream>>>(h1, h2, Wfc, bfc, out, n);
}

// Round 9
// 438.587 us; speedup vs baseline: 5.9022x; 1.1230x over previous
//
#include <hip/hip_runtime.h>
#include <math.h>

#define NCLS 40
#define BSZ 32          // dst nodes per bucket
#define BCAP 768        // slots per bucket (avg fill 512, P(overflow) ~ 1e-27)
#define CSTR 16         // cursor stride in ints: 1 counter per 64B line

using f16x8 = __attribute__((ext_vector_type(8))) _Float16;
using f16x2 = __attribute__((ext_vector_type(2))) _Float16;
using f32x4 = __attribute__((ext_vector_type(4))) float;

// ---------------- bucketed edge build ----------------
__global__ void init_cur(int* __restrict__ bcur, int nbk) {
  int i = blockIdx.x * 256 + threadIdx.x;
  if (i < nbk) bcur[i * CSTR] = i * BCAP;
}

// Partitioned append, grid-sized for FULL occupancy (R8: 832 blocks = 40% wave
// slots, latency-bound at 5% VALUBusy; 2048 blocks fills the machine, grid-
// stride keeps total reads fixed). (bucket&7)==blockIdx&7 matches round-robin
// block->XCD so each bucket region has one L2 owner (WRITE 92->62MB, R8).
__global__ __launch_bounds__(256) void append_part(const int* __restrict__ ei,
    const float* __restrict__ ew, int* __restrict__ bcur,
    int2* __restrict__ bedge, int e) {
  int part = blockIdx.x & 7;
  int grp = blockIdx.x >> 3;
  int ngrp = gridDim.x >> 3;
  for (int i = grp * 256 + threadIdx.x; i < e; i += ngrp * 256) {
    int d = ei[e + i];                 // dst row of edge_index
    int b = d >> 5;
    if ((b & 7) == part) {
      int slot = atomicAdd(&bcur[b * CSTR], 1);
      if (slot < b * BCAP + BCAP)      // overflow guard (never in practice)
        bedge[slot] = make_int2(ei[i] | ((d & 31) << 20), __float_as_int(ew[i]));
    }
  }
}

// ---------------- weight transpose + fp16 convert ----------------
__global__ void convert_wt(const float* __restrict__ W, _Float16* __restrict__ Wt) {
  int c = blockIdx.x;
  int k = threadIdx.x;
  Wt[c * 128 + k] = (_Float16)W[k * 128 + c];
}

// ------- MFMA GEMM: Y[n,128](f16) = A[n,128] @ W  (Wt = W^T, f16) -------
template<bool A32>
__global__ __launch_bounds__(256) void gemm_f16(const void* __restrict__ Av,
    const _Float16* __restrict__ Wt, _Float16* __restrict__ Y, int n) {
  __shared__ _Float16 Ys[64][136];   // bounce for coalesced stores
  int t = threadIdx.x;
  int wv = t >> 6, l = t & 63;
  int r0 = blockIdx.x * 64 + wv * 16;
  int arow = r0 + (l & 15);
  int kq = (l >> 4) * 8;
  bool rowok = arow < n;
  f32x4 acc[8] = {};
  for (int kc = 0; kc < 128; kc += 32) {
    f16x8 a = {};
    if (rowok) {
      if constexpr (A32) {
        const float* xp = (const float*)Av + (size_t)arow * 128 + kc + kq;
        float4 u0 = *(const float4*)xp;
        float4 u1 = *(const float4*)(xp + 4);
        a[0] = (_Float16)u0.x; a[1] = (_Float16)u0.y;
        a[2] = (_Float16)u0.z; a[3] = (_Float16)u0.w;
        a[4] = (_Float16)u1.x; a[5] = (_Float16)u1.y;
        a[6] = (_Float16)u1.z; a[7] = (_Float16)u1.w;
      } else {
        a = *(const f16x8*)((const _Float16*)Av + (size_t)arow * 128 + kc + kq);
      }
    }
    #pragma unroll
    for (int j = 0; j < 8; j++) {
      f16x8 b = *(const f16x8*)(Wt + (size_t)(j * 16 + (l & 15)) * 128 + kc + kq);
      acc[j] = __builtin_amdgcn_mfma_f32_16x16x32_f16(a, b, acc[j], 0, 0, 0);
    }
  }
  #pragma unroll
  for (int j = 0; j < 8; j++)
    #pragma unroll
    for (int i = 0; i < 4; i++)
      Ys[wv * 16 + (l >> 4) * 4 + i][j * 16 + (l & 15)] = (_Float16)acc[j][i];
  __syncthreads();
  int r = t >> 2;
  int c0 = (t & 3) * 32;
  int grow = blockIdx.x * 64 + r;
  if (grow < n) {
    #pragma unroll
    for (int i = 0; i < 4; i++) {
      f16x8 v = *(const f16x8*)&Ys[r][c0 + i * 8];
      *(f16x8*)(Y + (size_t)grow * 128 + c0 + i * 8) = v;
    }
  }
}

// -- fused bucket-sort + SpMM + self + bias + ReLU: H = relu(Y + A Y + b) --
// One block per 32-node bucket. Phase 1: LDS counting-sort of the bucket's
// edges into per-node lists (proven bucket2csr logic, now never hitting
// global). Phase 2: 4 waves x 8 nodes each, register accumulation; edge
// records broadcast-read from LDS (same address across wave = conflict-free).
__global__ __launch_bounds__(256) void spmm_sort_relu(const _Float16* __restrict__ Y,
    const int* __restrict__ bcur, const int2* __restrict__ bedge,
    const float* __restrict__ bias, _Float16* __restrict__ H, int n) {
  __shared__ int2 tmp[BCAP];          // 6 KB sorted edge image
  __shared__ int hist[BSZ], lpref[BSZ + 1], cur[BSZ];
  int t = threadIdx.x;
  int b = blockIdx.x;
  int cnt = min(bcur[b * CSTR] - b * BCAP, BCAP);
  if (t < BSZ) hist[t] = 0;
  __syncthreads();
  for (int i = t; i < cnt; i += 256)
    atomicAdd(&hist[(unsigned)bedge[b * BCAP + i].x >> 20], 1);
  __syncthreads();
  if (t == 0) {
    int a = 0;
    #pragma unroll
    for (int j = 0; j < BSZ; j++) { int v = hist[j]; lpref[j] = a; cur[j] = a; a += v; }
    lpref[BSZ] = a;
  }
  __syncthreads();
  for (int i = t; i < cnt; i += 256) {
    int2 r = bedge[b * BCAP + i];
    int dl = (unsigned)r.x >> 20;
    int pos = atomicAdd(&cur[dl], 1);
    tmp[pos] = make_int2(r.x & 0xFFFFF, r.y);   // strip dst-local bits
  }
  __syncthreads();
  int wv = t >> 6, lane = t & 63;
  int c = lane * 2;                   // 2 channels/lane -> 256B/wave gathers
  const _Float16* Yc = Y + c;
  for (int q = 0; q < 8; q++) {
    int dl = wv * 8 + q;              // wave handles 8 consecutive local nodes
    int node = b * BSZ + dl;
    if (node >= n) continue;
    int e0 = lpref[dl], e1 = lpref[dl + 1];
    float ax0 = 0.f, ay0 = 0.f, ax1 = 0.f, ay1 = 0.f;
    float ax2 = 0.f, ay2 = 0.f, ax3 = 0.f, ay3 = 0.f;
    int e = e0;
    for (; e + 3 < e1; e += 4) {      // 4 gathers in flight
      int2 p0 = tmp[e], p1 = tmp[e + 1], p2 = tmp[e + 2], p3 = tmp[e + 3];
      f16x2 v0 = *(const f16x2*)(Yc + (size_t)p0.x * 128);
      f16x2 v1 = *(const f16x2*)(Yc + (size_t)p1.x * 128);
      f16x2 v2 = *(const f16x2*)(Yc + (size_t)p2.x * 128);
      f16x2 v3 = *(const f16x2*)(Yc + (size_t)p3.x * 128);
      float w0 = __int_as_float(p0.y), w1 = __int_as_float(p1.y);
      float w2 = __int_as_float(p2.y), w3 = __int_as_float(p3.y);
      ax0 = fmaf(w0, (float)v0.x, ax0); ay0 = fmaf(w0, (float)v0.y, ay0);
      ax1 = fmaf(w1, (float)v1.x, ax1); ay1 = fmaf(w1, (float)v1.y, ay1);
      ax2 = fmaf(w2, (float)v2.x, ax2); ay2 = fmaf(w2, (float)v2.y, ay2);
      ax3 = fmaf(w3, (float)v3.x, ax3); ay3 = fmaf(w3, (float)v3.y, ay3);
    }
    for (; e < e1; e++) {
      int2 p0 = tmp[e];
      f16x2 v0 = *(const f16x2*)(Yc + (size_t)p0.x * 128);
      float w0 = __int_as_float(p0.y);
      ax0 = fmaf(w0, (float)v0.x, ax0); ay0 = fmaf(w0, (float)v0.y, ay0);
    }
    f16x2 yv = *(const f16x2*)(Yc + (size_t)node * 128);
    float2 bv = *(const float2*)(bias + c);
    float zx = (float)yv.x + (ax0 + ax1) + (ax2 + ax3) + bv.x;
    float zy = (float)yv.y + (ay0 + ay1) + (ay2 + ay3) + bv.y;
    f16x2 o;
    o.x = (_Float16)fmaxf(zx, 0.f);
    o.y = (_Float16)fmaxf(zy, 0.f);
    *(f16x2*)(H + (size_t)node * 128 + c) = o;
  }
}

// -------- FC over concat(h1,h2)(f16) + log_softmax (fp32 compute) --------
__global__ __launch_bounds__(256) void fc_lsm(const _Float16* __restrict__ H1,
    const _Float16* __restrict__ H2, const float* __restrict__ Wfc,
    const float* __restrict__ bfc, float* __restrict__ out, int n) {
  __shared__ float Wl[256 * NCLS];        // 40 KB, [k][c] layout
  __shared__ float Hs[64][132];           // 33 KB, transposed chunk Hs[k][r]
  int t = threadIdx.x;
  for (int i = t; i < 256 * NCLS; i += 256) Wl[i] = Wfc[i];
  int tx = t & 7, ty = t >> 3;            // tx: 5-col group (8x5=40), ty: 4-row group
  int row0 = blockIdx.x * 128;
  float acc[4][5] = {};
  for (int kc = 0; kc < 256; kc += 64) {
    {
      int r = t & 127;
      int half = t >> 7;
      int row = row0 + r;
      const _Float16* src = (kc < 128)
          ? (H1 + (size_t)row * 128 + kc + half * 32)
          : (H2 + (size_t)row * 128 + (kc - 128) + half * 32);
      if (row < n) {
        #pragma unroll
        for (int i = 0; i < 4; i++) {
          f16x8 v = ((const f16x8*)src)[i];
          #pragma unroll
          for (int q = 0; q < 8; q++) Hs[half * 32 + i * 8 + q][r] = (float)v[q];
        }
      } else {
        #pragma unroll
        for (int k = 0; k < 32; k++) Hs[half * 32 + k][r] = 0.f;
      }
    }
    __syncthreads();
    #pragma unroll 4
    for (int k = 0; k < 64; k++) {
      float4 a = *(const float4*)&Hs[k][ty * 4];
      const float* wrow = &Wl[(kc + k) * NCLS + tx * 5];
      float b_[5];
      #pragma unroll
      for (int j = 0; j < 5; j++) b_[j] = wrow[j];
      #pragma unroll
      for (int j = 0; j < 5; j++) {
        acc[0][j] = fmaf(a.x, b_[j], acc[0][j]);
        acc[1][j] = fmaf(a.y, b_[j], acc[1][j]);
        acc[2][j] = fmaf(a.z, b_[j], acc[2][j]);
        acc[3][j] = fmaf(a.w, b_[j], acc[3][j]);
      }
    }
    __syncthreads();
  }
  int c0 = tx * 5;
  float bv[5];
  #pragma unroll
  for (int j = 0; j < 5; j++) bv[j] = bfc[c0 + j];
  #pragma unroll
  for (int i = 0; i < 4; i++) {
    float lg[5];
    #pragma unroll
    for (int j = 0; j < 5; j++) lg[j] = acc[i][j] + bv[j];
    float m = lg[0];
    #pragma unroll
    for (int j = 1; j < 5; j++) m = fmaxf(m, lg[j]);
    m = fmaxf(m, __shfl_xor(m, 1));
    m = fmaxf(m, __shfl_xor(m, 2));
    m = fmaxf(m, __shfl_xor(m, 4));       // 8 lanes (same ty) own one row's 40 cols
    float ssum = 0.f;
    #pragma unroll
    for (int j = 0; j < 5; j++) ssum += __expf(lg[j] - m);
    ssum += __shfl_xor(ssum, 1);
    ssum += __shfl_xor(ssum, 2);
    ssum += __shfl_xor(ssum, 4);
    float lse = m + __logf(ssum);
    int row = row0 + ty * 4 + i;
    if (row < n) {
      #pragma unroll
      for (int j = 0; j < 5; j++) out[(size_t)row * NCLS + c0 + j] = lg[j] - lse;
    }
  }
}

extern "C" void kernel_launch(void* const* d_in, const int* in_sizes, int n_in,
                              void* d_out, int out_size, void* d_ws, size_t ws_size,
                              hipStream_t stream) {
  const float* x   = (const float*)d_in[0];
  const int*   ei  = (const int*)d_in[1];
  const float* ew  = (const float*)d_in[2];
  const float* W1  = (const float*)d_in[3];
  const float* b1  = (const float*)d_in[4];
  const float* W2  = (const float*)d_in[5];
  const float* b2  = (const float*)d_in[6];
  const float* Wfc = (const float*)d_in[7];
  const float* bfc = (const float*)d_in[8];
  float* out = (float*)d_out;
  int n = in_sizes[0] / 128;     // 100000
  int e = in_sizes[2];           // 1600000
  int nbk = (n + BSZ - 1) / BSZ; // 3125 buckets

  // workspace partition (~90 MB)
  char* ws = (char*)d_ws;
  size_t off = 0;
  auto alloc = [&](size_t bytes) -> void* {
    void* p = ws + off; off += (bytes + 255) & ~(size_t)255; return p;
  };
  int*      bcur  = (int*)alloc((size_t)nbk * CSTR * 4);  // line-padded cursors
  int2*     bedge = (int2*)alloc((size_t)nbk * BCAP * 8);
  _Float16* w1t   = (_Float16*)alloc(128 * 128 * 2);
  _Float16* w2t   = (_Float16*)alloc(128 * 128 * 2);
  _Float16* y     = (_Float16*)alloc((size_t)n * 128 * 2);
  _Float16* h1    = (_Float16*)alloc((size_t)n * 128 * 2);
  _Float16* h2    = (_Float16*)alloc((size_t)n * 128 * 2);

  // bucketed edge build (full-occupancy grid)
  init_cur<<<(nbk + 255) / 256, 256, 0, stream>>>(bcur, nbk);
  append_part<<<8 * 256, 256, 0, stream>>>(ei, ew, bcur, bedge, e);

  // weight converts
  convert_wt<<<128, 128, 0, stream>>>(W1, w1t);
  convert_wt<<<128, 128, 0, stream>>>(W2, w2t);

  int gb = (n + 63) / 64;
  // layer 1: y = x@W1 ; h1 = relu(y + A y + b1)   (x fp32 read fused)
  gemm_f16<true><<<gb, 256, 0, stream>>>((const void*)x, w1t, y, n);
  spmm_sort_relu<<<nbk, 256, 0, stream>>>(y, bcur, bedge, b1, h1, n);
  // layer 2: y = h1@W2 ; h2 = relu(y + A y + b2)
  gemm_f16<false><<<gb, 256, 0, stream>>>((const void*)h1, w2t, y, n);
  spmm_sort_relu<<<nbk, 256, 0, stream>>>(y, bcur, bedge, b2, h2, n);
  // FC + log_softmax
  fc_lsm<<<(n + 127) / 128, 256, 0, stream>>>(h1, h2, Wfc, bfc, out, n);
}